// Round 1
// baseline (103.084 us; speedup 1.0000x reference)
//
#include <hip/hip_runtime.h>
#include <hip/hip_bf16.h>

typedef __attribute__((ext_vector_type(4))) float f32x4;
typedef __attribute__((ext_vector_type(8))) short short8;

#define NB 8192
#define ND 256
#define NK 32
#define NN 512   // W_mu rows (256) + W_sig rows (256)

static __device__ __forceinline__ unsigned short f2bf(float f) {
  return __builtin_bit_cast(unsigned short, __float2bfloat16(f));
}

// ---- kernel 0a: convert embedded_state fp32 -> bf16 -------------------------
__global__ __launch_bounds__(256) void conv_x_k(const float4* __restrict__ x,
                                                ushort4* __restrict__ xb) {
  int i = blockIdx.x * 256 + threadIdx.x;   // covers NB*ND/4 = 524288
  float4 v = x[i];
  ushort4 o;
  o.x = f2bf(v.x); o.y = f2bf(v.y); o.z = f2bf(v.z); o.w = f2bf(v.w);
  xb[i] = o;
}

// ---- kernel 0b: stack W_mu,W_sig -> bf16 [512][256] -------------------------
__global__ __launch_bounds__(256) void conv_w_k(const float* __restrict__ wmu,
                                                const float* __restrict__ wsig,
                                                __hip_bfloat16* __restrict__ wb) {
  int i = blockIdx.x * 256 + threadIdx.x;   // 512 blocks -> 131072
  float v = (i < 65536) ? wmu[i] : wsig[i - 65536];
  wb[i] = __float2bfloat16(v);
}

// ---- kernel 0c: cluster constants ------------------------------------------
// mcv[d][k] = {mu_c[k,d], exp(-lsc[k,d])}  (transposed for conflict-free reads)
// slsc[k]   = sum_d lsc[k,d]
__global__ __launch_bounds__(256) void prep_cluster_k(const float* __restrict__ mu_c,
                                                      const float* __restrict__ lsc,
                                                      float2* __restrict__ mcv,
                                                      float* __restrict__ slsc) {
  int k = blockIdx.x;        // 32 blocks
  int d = threadIdx.x;       // 256 threads
  float l = lsc[k * ND + d];
  float2 v; v.x = mu_c[k * ND + d]; v.y = __expf(-l);
  mcv[d * NK + k] = v;
  // block reduction of l
  float s = l;
  #pragma unroll
  for (int sh = 32; sh; sh >>= 1) s += __shfl_xor(s, sh);
  __shared__ float red[4];
  int lane = threadIdx.x & 63, wv = threadIdx.x >> 6;
  if (lane == 0) red[wv] = s;
  __syncthreads();
  if (threadIdx.x == 0) slsc[k] = red[0] + red[1] + red[2] + red[3];
}

// ---- kernel 1: GEMM  C[b,n] = sum_d x[b,d]*Wcat[n,d]  (bf16 MFMA) ----------
// n<256 -> muz[b,n] = C + b_mu[n]
// n>=256 -> sigq[b,n-256] = exp(C + b_sig[n-256])
__global__ __launch_bounds__(256) void gemm_k(const __hip_bfloat16* __restrict__ xbf,
                                              const __hip_bfloat16* __restrict__ wbf,
                                              const float* __restrict__ bmu,
                                              const float* __restrict__ bsig,
                                              float* __restrict__ muz,
                                              float* __restrict__ sigq) {
  const int m0 = blockIdx.x * 128;   // 64 blocks
  const int n0 = blockIdx.y * 128;   // 4 blocks
  __shared__ __align__(16) __hip_bfloat16 At[128][72];  // +8 pad: bank-spread
  __shared__ __align__(16) __hip_bfloat16 Bt[128][72];
  __shared__ float bias_s[128];
  const int tid = threadIdx.x;
  const int lane = tid & 63;
  const int wv = tid >> 6;
  const int wr = wv >> 1, wc = wv & 1;   // 2x2 waves, each 64x64 out

  if (tid < 128) {
    int col = n0 + tid;
    bias_s[tid] = (col < ND) ? bmu[col] : bsig[col - ND];
  }

  f32x4 acc[4][4];
  #pragma unroll
  for (int a = 0; a < 4; ++a)
    #pragma unroll
    for (int b = 0; b < 4; ++b) acc[a][b] = (f32x4){0.f, 0.f, 0.f, 0.f};

  const int lrow = lane & 15;
  const int lko  = (lane >> 4) * 8;

  for (int kt = 0; kt < 4; ++kt) {
    const int k0 = kt * 64;
    __syncthreads();
    // stage 128x64 bf16 tiles (reg path)
    #pragma unroll
    for (int j = 0; j < 4; ++j) {
      int i = tid + j * 256;              // 0..1023
      int row = i >> 3, kc = i & 7;
      short8 va = *reinterpret_cast<const short8*>(&xbf[(size_t)(m0 + row) * ND + k0 + kc * 8]);
      *reinterpret_cast<short8*>(&At[row][kc * 8]) = va;
      short8 vb = *reinterpret_cast<const short8*>(&wbf[(size_t)(n0 + row) * ND + k0 + kc * 8]);
      *reinterpret_cast<short8*>(&Bt[row][kc * 8]) = vb;
    }
    __syncthreads();

    short8 aF[4][2], bF[4][2];
    #pragma unroll
    for (int mf = 0; mf < 4; ++mf)
      #pragma unroll
      for (int kk = 0; kk < 2; ++kk)
        aF[mf][kk] = *reinterpret_cast<const short8*>(&At[wr * 64 + mf * 16 + lrow][kk * 32 + lko]);
    #pragma unroll
    for (int nf = 0; nf < 4; ++nf)
      #pragma unroll
      for (int kk = 0; kk < 2; ++kk)
        bF[nf][kk] = *reinterpret_cast<const short8*>(&Bt[wc * 64 + nf * 16 + lrow][kk * 32 + lko]);

    #pragma unroll
    for (int mf = 0; mf < 4; ++mf)
      #pragma unroll
      for (int nf = 0; nf < 4; ++nf) {
        acc[mf][nf] = __builtin_amdgcn_mfma_f32_16x16x32_bf16(aF[mf][0], bF[nf][0], acc[mf][nf], 0, 0, 0);
        acc[mf][nf] = __builtin_amdgcn_mfma_f32_16x16x32_bf16(aF[mf][1], bF[nf][1], acc[mf][nf], 0, 0, 0);
      }
  }

  // epilogue: C/D layout col=lane&15, row=(lane>>4)*4+j  [measured m89/m91]
  const bool isMu = (n0 < ND);
  #pragma unroll
  for (int mf = 0; mf < 4; ++mf)
    #pragma unroll
    for (int nf = 0; nf < 4; ++nf) {
      int rbase = m0 + wr * 64 + mf * 16 + ((lane >> 4) * 4);
      int coll  = wc * 64 + nf * 16 + (lane & 15);
      int col   = n0 + coll;
      #pragma unroll
      for (int j = 0; j < 4; ++j) {
        float v = acc[mf][nf][j] + bias_s[coll];
        size_t r = (size_t)(rbase + j);
        if (isMu) muz[r * ND + col] = v;
        else      sigq[r * ND + (col - ND)] = __expf(v);
      }
    }
}

// ---- kernel 2: z = muz + sqrt(sigq)*eps  -> d_out[0 .. B*D) ----------------
__global__ __launch_bounds__(256) void z_k(const float4* __restrict__ muz,
                                           const float4* __restrict__ sigq,
                                           const float4* __restrict__ eps,
                                           float4* __restrict__ zout) {
  int i = blockIdx.x * 256 + threadIdx.x;   // 524288
  float4 m = muz[i], s = sigq[i], e = eps[i];
  float4 o;
  o.x = m.x + sqrtf(s.x) * e.x;
  o.y = m.y + sqrtf(s.y) * e.y;
  o.z = m.z + sqrtf(s.z) * e.z;
  o.w = m.w + sqrtf(s.w) * e.w;
  zout[i] = o;
}

// ---- kernel 3: per-b cluster logits + softmax + loss partials --------------
// 512 blocks x 256 thr (4 waves); each block handles 16 b rows.
// lane: k = lane&31, h = lane>>5 (half of D). part[blk][33] = {piSum[32], gauss}
__global__ __launch_bounds__(256) void cluster_k(const float* __restrict__ zq,
                                                 const float* __restrict__ muz,
                                                 const float* __restrict__ sigq,
                                                 const float2* __restrict__ mcv,
                                                 const float* __restrict__ slsc,
                                                 float* __restrict__ part) {
  __shared__ float2 mcv_s[ND][NK];     // 64 KiB
  __shared__ float4 zms[4][ND];        // 16 KiB  {z, muz, sigq, -}
  __shared__ float sAcc[33];
  const int tid = threadIdx.x;
  for (int i = tid; i < ND * NK; i += 256) mcv_s[i >> 5][i & 31] = mcv[i];
  if (tid < 33) sAcc[tid] = 0.f;
  const int wv = tid >> 6, lane = tid & 63;
  const int k = lane & 31, h = lane >> 5;
  const float slk = slsc[k];
  __syncthreads();

  for (int it = 0; it < 4; ++it) {
    const int b = blockIdx.x * 16 + it * 4 + wv;
    const float* zr = zq   + (size_t)b * ND;
    const float* mr = muz  + (size_t)b * ND;
    const float* sr = sigq + (size_t)b * ND;
    for (int d = lane; d < ND; d += 64)
      zms[wv][d] = make_float4(zr[d], mr[d], sr[d], 0.f);
    // same-wave LDS RAW: in-order LDS per wave, compiler orders through __shared__

    float al = 0.f, av = 0.f;
    #pragma unroll 8
    for (int dd = 0; dd < 128; ++dd) {
      int d = h * 128 + dd;
      float4 t = zms[wv][d];
      float2 mc = mcv_s[d][k];
      float e1 = t.x - mc.x;           // z - mu_c
      float e2 = t.y - mc.x;           // muz - mu_c
      al = fmaf(e1 * e1, mc.y, al);
      av = fmaf(e2 * e2 + t.z, mc.y, av);
    }
    al += __shfl_xor(al, 32);
    av += __shfl_xor(av, 32);
    float logit = -al;
    float Ck = slk + av;
    float mx = logit;
    #pragma unroll
    for (int s = 16; s; s >>= 1) mx = fmaxf(mx, __shfl_xor(mx, s));
    float p = __expf(logit - mx);
    float ps = p;
    #pragma unroll
    for (int s = 16; s; s >>= 1) ps += __shfl_xor(ps, s);
    float pi = p / ps + 1e-10f;
    float g = pi * Ck;
    #pragma unroll
    for (int s = 16; s; s >>= 1) g += __shfl_xor(g, s);
    if (lane < 32) atomicAdd(&sAcc[k], pi);
    if (lane == 0) atomicAdd(&sAcc[32], 0.5f * g);
  }
  __syncthreads();
  if (tid < 33) part[blockIdx.x * 33 + tid] = sAcc[tid];
}

// ---- kernel 4: final reduce ------------------------------------------------
__global__ void final_k(const float* __restrict__ part, float* __restrict__ out) {
  int lane = threadIdx.x;   // 1 block, 64 threads
  double acc = 0.0;
  if (lane < 33)
    for (int bk = 0; bk < 512; ++bk) acc += (double)part[bk * 33 + lane];
  double g = __shfl(acc, 32);
  double t = 0.0;
  if (lane < 32) {
    double mk = acc / (double)NB;     // mean_pi[k]
    t = mk * log(mk);
  }
  #pragma unroll
  for (int s = 16; s; s >>= 1) t += __shfl_xor(t, s);
  if (lane == 0) {
    out[NB * ND]     = (float)g;            // batch_gaussian_loss (0.5 applied)
    out[NB * ND + 1] = (float)(t / (double)NK);  // batch_uniform_loss
  }
}

extern "C" void kernel_launch(void* const* d_in, const int* in_sizes, int n_in,
                              void* d_out, int out_size, void* d_ws, size_t ws_size,
                              hipStream_t stream) {
  const float* x    = (const float*)d_in[0];
  const float* eps  = (const float*)d_in[1];
  const float* wmu  = (const float*)d_in[2];
  const float* bmu  = (const float*)d_in[3];
  const float* wsig = (const float*)d_in[4];
  const float* bsig = (const float*)d_in[5];
  const float* mu_c = (const float*)d_in[6];
  const float* lsc  = (const float*)d_in[7];
  float* out = (float*)d_out;

  char* ws = (char*)d_ws;
  __hip_bfloat16* xbf = (__hip_bfloat16*)ws;                          // 4 MiB
  __hip_bfloat16* wbf = (__hip_bfloat16*)(ws + (4u << 20));           // 256 KiB
  float*  muz  = (float*)(ws + (4u << 20) + (256u << 10));            // 8 MiB
  float*  sigq = (float*)(ws + (12u << 20) + (256u << 10));           // 8 MiB
  float2* mcv  = (float2*)(ws + (20u << 20) + (256u << 10));          // 64 KiB
  float*  slsc = (float*)(ws + (20u << 20) + (320u << 10));           // 128 B
  float*  part = (float*)(ws + (20u << 20) + (320u << 10) + 256u);    // ~68 KiB

  conv_x_k<<<2048, 256, 0, stream>>>((const float4*)x, (ushort4*)xbf);
  conv_w_k<<<512, 256, 0, stream>>>(wmu, wsig, wbf);
  prep_cluster_k<<<32, 256, 0, stream>>>(mu_c, lsc, mcv, slsc);
  gemm_k<<<dim3(64, 4), 256, 0, stream>>>(xbf, wbf, bmu, bsig, muz, sigq);
  z_k<<<2048, 256, 0, stream>>>((const float4*)muz, (const float4*)sigq,
                                (const float4*)eps, (float4*)out);
  cluster_k<<<512, 256, 0, stream>>>(out, muz, sigq, mcv, slsc, part);
  final_k<<<1, 64, 0, stream>>>(part, out);
}

// Round 2
// 46.073 us; speedup vs baseline: 2.2374x; 2.2374x over previous
//
#include <hip/hip_runtime.h>
#include <hip/hip_bf16.h>

typedef __attribute__((ext_vector_type(4))) float f32x4;
typedef __attribute__((ext_vector_type(8))) short short8;

#define NB 8192
#define ND 256
#define NK 32

static __device__ __forceinline__ unsigned short f2bf(float f) {
  return __builtin_bit_cast(unsigned short, __float2bfloat16(f));
}

// ---- kernel 0: fused prep ---------------------------------------------------
// blocks [0,2048)    : x fp32 -> bf16 (float4 granularity)
// blocks [2048,2560) : Wcat = [W_mu; W_sig] -> bf16 [512][256]
// blocks [2560,2592) : per-k cluster consts + Bc bf16 [32][512]
//   Bc[k][d]     = exp(-lsc[k,d])
//   Bc[k][256+d] = -2 * mu_c[k,d] * exp(-lsc[k,d])
//   c3k[k] = sum_d mu_c^2 * inv ;  ckk[k] = sum_d lsc + c3k[k]
__global__ __launch_bounds__(256) void prep_k(const float4* __restrict__ x,
                                              ushort4* __restrict__ xb,
                                              const float* __restrict__ wmu,
                                              const float* __restrict__ wsig,
                                              __hip_bfloat16* __restrict__ wb,
                                              const float* __restrict__ mu_c,
                                              const float* __restrict__ lsc,
                                              __hip_bfloat16* __restrict__ Bc,
                                              float* __restrict__ c3k,
                                              float* __restrict__ ckk) {
  __shared__ float red1[4], red2[4];
  const int blk = blockIdx.x, tid = threadIdx.x;
  if (blk < 2048) {
    int i = blk * 256 + tid;
    float4 v = x[i];
    ushort4 o;
    o.x = f2bf(v.x); o.y = f2bf(v.y); o.z = f2bf(v.z); o.w = f2bf(v.w);
    xb[i] = o;
  } else if (blk < 2560) {
    int i = (blk - 2048) * 256 + tid;
    float v = (i < 65536) ? wmu[i] : wsig[i - 65536];
    wb[i] = __float2bfloat16(v);
  } else {
    int k = blk - 2560;
    int d = tid;
    float l = lsc[k * ND + d];
    float inv = __expf(-l);
    float mc = mu_c[k * ND + d];
    Bc[k * 512 + d]       = __float2bfloat16(inv);
    Bc[k * 512 + 256 + d] = __float2bfloat16(-2.f * mc * inv);
    float s1 = l, s2 = mc * mc * inv;
    #pragma unroll
    for (int sh = 32; sh; sh >>= 1) { s1 += __shfl_xor(s1, sh); s2 += __shfl_xor(s2, sh); }
    int lane = tid & 63, wv = tid >> 6;
    if (lane == 0) { red1[wv] = s1; red2[wv] = s2; }
    __syncthreads();
    if (tid == 0) {
      float t1 = red1[0] + red1[1] + red1[2] + red1[3];
      float t2 = red2[0] + red2[1] + red2[2] + red2[3];
      c3k[k] = t2;
      ckk[k] = t1 + t2;
    }
  }
}

// ---- kernel 1: GEMM + z + cluster-A construction ---------------------------
// grid (64, 4), 256 thr. Block: 128 b-rows x 64 d-cols, computing BOTH
// muz[b,d] and log_sigma_sq[b,d] via interleaved B-tile rows:
//   tile row r -> Wcat row  ((r>>4)&1)*256 + by*64 + (r>>5)*16 + (r&15)
// so wave (wr,wc) fragment nf: even nf = mu, odd nf = sig, at the same d.
// Epilogue (all in-register):
//   z = muz + sqrt(exp(ls))*eps        -> d_out
//   Ac[b][d]=bf16(z^2)  Ac[b][256+d]=bf16(z)
//   Aq[b][d]=bf16(sigq+muz^2)  Aq[b][256+d]=bf16(muz)
__global__ __launch_bounds__(256) void gemm1_k(const __hip_bfloat16* __restrict__ xbf,
                                               const __hip_bfloat16* __restrict__ wbf,
                                               const float* __restrict__ bmu,
                                               const float* __restrict__ bsigv,
                                               const float* __restrict__ eps,
                                               float* __restrict__ zout,
                                               __hip_bfloat16* __restrict__ Ac,
                                               __hip_bfloat16* __restrict__ Aq) {
  const int m0 = blockIdx.x * 128;
  const int n0 = blockIdx.y * 64;      // d-range base (width 64)
  __shared__ __align__(16) __hip_bfloat16 At[128][72];
  __shared__ __align__(16) __hip_bfloat16 Bt[128][72];
  const int tid = threadIdx.x;
  const int lane = tid & 63;
  const int wv = tid >> 6;
  const int wr = wv >> 1, wc = wv & 1;     // 2x2 waves, each 64x64 out
  const int lrow = lane & 15;
  const int lko  = (lane >> 4) * 8;

  f32x4 acc[4][4];
  #pragma unroll
  for (int a = 0; a < 4; ++a)
    #pragma unroll
    for (int b = 0; b < 4; ++b) acc[a][b] = (f32x4){0.f, 0.f, 0.f, 0.f};

  for (int kt = 0; kt < 4; ++kt) {
    const int k0 = kt * 64;
    __syncthreads();
    #pragma unroll
    for (int j = 0; j < 4; ++j) {
      int i = tid + j * 256;             // 0..1023
      int row = i >> 3, kc = i & 7;
      short8 va = *reinterpret_cast<const short8*>(&xbf[(size_t)(m0 + row) * ND + k0 + kc * 8]);
      *reinterpret_cast<short8*>(&At[row][kc * 8]) = va;
      int wsel = (row >> 4) & 1;
      int dloc = (row >> 5) * 16 + (row & 15);
      int wrow = wsel * 256 + n0 + dloc;
      short8 vb = *reinterpret_cast<const short8*>(&wbf[(size_t)wrow * ND + k0 + kc * 8]);
      *reinterpret_cast<short8*>(&Bt[row][kc * 8]) = vb;
    }
    __syncthreads();

    short8 aF[4][2], bF[4][2];
    #pragma unroll
    for (int mf = 0; mf < 4; ++mf)
      #pragma unroll
      for (int kk = 0; kk < 2; ++kk)
        aF[mf][kk] = *reinterpret_cast<const short8*>(&At[wr * 64 + mf * 16 + lrow][kk * 32 + lko]);
    #pragma unroll
    for (int nf = 0; nf < 4; ++nf)
      #pragma unroll
      for (int kk = 0; kk < 2; ++kk)
        bF[nf][kk] = *reinterpret_cast<const short8*>(&Bt[wc * 64 + nf * 16 + lrow][kk * 32 + lko]);

    #pragma unroll
    for (int mf = 0; mf < 4; ++mf)
      #pragma unroll
      for (int nf = 0; nf < 4; ++nf) {
        acc[mf][nf] = __builtin_amdgcn_mfma_f32_16x16x32_bf16(aF[mf][0], bF[nf][0], acc[mf][nf], 0, 0, 0);
        acc[mf][nf] = __builtin_amdgcn_mfma_f32_16x16x32_bf16(aF[mf][1], bF[nf][1], acc[mf][nf], 0, 0, 0);
      }
  }

  // epilogue: C/D layout col=lane&15, row=(lane>>4)*4+j
  // d = n0 + wc*32 + dp*16 + (lane&15);  mu plane = acc[mf][2dp], sig = acc[mf][2dp+1]
  float bm[2], bs[2];
  #pragma unroll
  for (int dp = 0; dp < 2; ++dp) {
    int d = n0 + wc * 32 + dp * 16 + lrow;
    bm[dp] = bmu[d];
    bs[dp] = bsigv[d];
  }
  #pragma unroll
  for (int mf = 0; mf < 4; ++mf) {
    int bb = m0 + wr * 64 + mf * 16 + ((lane >> 4) * 4);
    #pragma unroll
    for (int dp = 0; dp < 2; ++dp) {
      int d = n0 + wc * 32 + dp * 16 + lrow;
      #pragma unroll
      for (int j = 0; j < 4; ++j) {
        int b = bb + j;
        float muv = acc[mf][dp * 2][j] + bm[dp];
        float lsv = acc[mf][dp * 2 + 1][j] + bs[dp];
        float sq  = __expf(lsv);
        float e   = eps[(size_t)b * ND + d];
        float zv  = muv + sqrtf(sq) * e;
        zout[(size_t)b * ND + d] = zv;
        size_t ro = (size_t)b * 512;
        Ac[ro + d]       = __float2bfloat16(zv * zv);
        Ac[ro + 256 + d] = __float2bfloat16(zv);
        Aq[ro + d]       = __float2bfloat16(sq + muv * muv);
        Aq[ro + 256 + d] = __float2bfloat16(muv);
      }
    }
  }
}

// ---- kernel 2: cluster GEMMs + softmax + loss partials ---------------------
// 128 blocks x 256 thr; wave wv owns 16 b-rows (m0 = blk*64 + wv*16).
// Two MFMA chains over K=512 sharing B [32][512]; no LDS staging (A has no
// cross-wave reuse; B is L2-resident).
__global__ __launch_bounds__(256) void cluster2_k(const __hip_bfloat16* __restrict__ Ac,
                                                  const __hip_bfloat16* __restrict__ Aq,
                                                  const __hip_bfloat16* __restrict__ Bc,
                                                  const float* __restrict__ c3k,
                                                  const float* __restrict__ ckk,
                                                  float* __restrict__ part) {
  __shared__ float sW[4][33];
  const int tid = threadIdx.x, lane = tid & 63, wv = tid >> 6;
  const int lrow = lane & 15, lko = (lane >> 4) * 8;
  const int m0 = blockIdx.x * 64 + wv * 16;

  f32x4 accL[2], accQ[2];
  accL[0] = accL[1] = accQ[0] = accQ[1] = (f32x4){0.f, 0.f, 0.f, 0.f};

  const __hip_bfloat16* arc = Ac + (size_t)(m0 + lrow) * 512 + lko;
  const __hip_bfloat16* arq = Aq + (size_t)(m0 + lrow) * 512 + lko;
  const __hip_bfloat16* br0 = Bc + (size_t)lrow * 512 + lko;          // k-rows 0..15
  const __hip_bfloat16* br1 = Bc + (size_t)(16 + lrow) * 512 + lko;   // k-rows 16..31

  #pragma unroll 2
  for (int ch = 0; ch < 8; ++ch) {
    const int k0 = ch * 64;
    short8 ac0 = *reinterpret_cast<const short8*>(arc + k0);
    short8 ac1 = *reinterpret_cast<const short8*>(arc + k0 + 32);
    short8 aq0 = *reinterpret_cast<const short8*>(arq + k0);
    short8 aq1 = *reinterpret_cast<const short8*>(arq + k0 + 32);
    short8 b00 = *reinterpret_cast<const short8*>(br0 + k0);
    short8 b01 = *reinterpret_cast<const short8*>(br0 + k0 + 32);
    short8 b10 = *reinterpret_cast<const short8*>(br1 + k0);
    short8 b11 = *reinterpret_cast<const short8*>(br1 + k0 + 32);
    accL[0] = __builtin_amdgcn_mfma_f32_16x16x32_bf16(ac0, b00, accL[0], 0, 0, 0);
    accL[0] = __builtin_amdgcn_mfma_f32_16x16x32_bf16(ac1, b01, accL[0], 0, 0, 0);
    accL[1] = __builtin_amdgcn_mfma_f32_16x16x32_bf16(ac0, b10, accL[1], 0, 0, 0);
    accL[1] = __builtin_amdgcn_mfma_f32_16x16x32_bf16(ac1, b11, accL[1], 0, 0, 0);
    accQ[0] = __builtin_amdgcn_mfma_f32_16x16x32_bf16(aq0, b00, accQ[0], 0, 0, 0);
    accQ[0] = __builtin_amdgcn_mfma_f32_16x16x32_bf16(aq1, b01, accQ[0], 0, 0, 0);
    accQ[1] = __builtin_amdgcn_mfma_f32_16x16x32_bf16(aq0, b10, accQ[1], 0, 0, 0);
    accQ[1] = __builtin_amdgcn_mfma_f32_16x16x32_bf16(aq1, b11, accQ[1], 0, 0, 0);
  }

  // epilogue: lane holds rows (lane>>4)*4+j of wave's 16, cols k = nf*16 + lrow
  const float c3a = c3k[lrow], c3b = c3k[16 + lrow];
  const float cka = ckk[lrow], ckb = ckk[16 + lrow];
  float gacc = 0.f, pisA = 0.f, pisB = 0.f;
  #pragma unroll
  for (int j = 0; j < 4; ++j) {
    float l0 = -(accL[0][j] + c3a);
    float l1 = -(accL[1][j] + c3b);
    float mx = fmaxf(l0, l1);
    #pragma unroll
    for (int s = 8; s; s >>= 1) mx = fmaxf(mx, __shfl_xor(mx, s));
    float p0 = __expf(l0 - mx), p1 = __expf(l1 - mx);
    float ps = p0 + p1;
    #pragma unroll
    for (int s = 8; s; s >>= 1) ps += __shfl_xor(ps, s);
    float pi0 = p0 / ps + 1e-10f;
    float pi1 = p1 / ps + 1e-10f;
    float C0 = accQ[0][j] + cka;
    float C1 = accQ[1][j] + ckb;
    float g = pi0 * C0 + pi1 * C1;
    #pragma unroll
    for (int s = 8; s; s >>= 1) g += __shfl_xor(g, s);
    gacc += g;                 // all lanes in 16-group share g
    pisA += pi0; pisB += pi1;
  }
  // sum pi over the wave's 4 row-groups
  pisA += __shfl_xor(pisA, 16); pisA += __shfl_xor(pisA, 32);
  pisB += __shfl_xor(pisB, 16); pisB += __shfl_xor(pisB, 32);
  gacc += __shfl_xor(gacc, 16); gacc += __shfl_xor(gacc, 32);
  if (lane < 16) { sW[wv][lane] = pisA; sW[wv][16 + lane] = pisB; }
  if (lane == 0) sW[wv][32] = 0.5f * gacc;
  __syncthreads();
  if (tid < 33)
    part[blockIdx.x * 33 + tid] = sW[0][tid] + sW[1][tid] + sW[2][tid] + sW[3][tid];
}

// ---- kernel 3: final reduce ------------------------------------------------
__global__ void final_k(const float* __restrict__ part, float* __restrict__ out) {
  int lane = threadIdx.x;   // 1 block, 64 threads
  double acc = 0.0;
  if (lane < 33)
    for (int bk = 0; bk < 128; ++bk) acc += (double)part[bk * 33 + lane];
  double g = __shfl(acc, 32);
  double t = 0.0;
  if (lane < 32) {
    double mk = acc / (double)NB;
    t = mk * log(mk);
  }
  #pragma unroll
  for (int s = 16; s; s >>= 1) t += __shfl_xor(t, s);
  if (lane == 0) {
    out[NB * ND]     = (float)g;                 // batch_gaussian_loss
    out[NB * ND + 1] = (float)(t / (double)NK);  // batch_uniform_loss
  }
}

extern "C" void kernel_launch(void* const* d_in, const int* in_sizes, int n_in,
                              void* d_out, int out_size, void* d_ws, size_t ws_size,
                              hipStream_t stream) {
  const float* x    = (const float*)d_in[0];
  const float* eps  = (const float*)d_in[1];
  const float* wmu  = (const float*)d_in[2];
  const float* bmu  = (const float*)d_in[3];
  const float* wsig = (const float*)d_in[4];
  const float* bsig = (const float*)d_in[5];
  const float* mu_c = (const float*)d_in[6];
  const float* lsc  = (const float*)d_in[7];
  float* out = (float*)d_out;

  char* ws = (char*)d_ws;
  __hip_bfloat16* xbf = (__hip_bfloat16*)ws;                             // 4 MiB
  __hip_bfloat16* wbf = (__hip_bfloat16*)(ws + (4u << 20));              // 256 KiB
  __hip_bfloat16* Ac  = (__hip_bfloat16*)(ws + (4u << 20) + (256u << 10));   // 8 MiB
  __hip_bfloat16* Aq  = (__hip_bfloat16*)(ws + (12u << 20) + (256u << 10));  // 8 MiB
  __hip_bfloat16* Bc  = (__hip_bfloat16*)(ws + (20u << 20) + (256u << 10));  // 32 KiB
  float* c3k  = (float*)(ws + (20u << 20) + (288u << 10));               // 128 B
  float* ckk  = (float*)(ws + (20u << 20) + (288u << 10) + 256u);        // 128 B
  float* part = (float*)(ws + (20u << 20) + (288u << 10) + 512u);        // ~17 KiB

  prep_k<<<2592, 256, 0, stream>>>((const float4*)x, (ushort4*)xbf,
                                   wmu, wsig, wbf, mu_c, lsc, Bc, c3k, ckk);
  gemm1_k<<<dim3(64, 4), 256, 0, stream>>>(xbf, wbf, bmu, bsig, eps, out, Ac, Aq);
  cluster2_k<<<128, 256, 0, stream>>>(Ac, Aq, Bc, c3k, ckk, part);
  final_k<<<1, 64, 0, stream>>>(part, out);
}